// Round 8
// baseline (10303.018 us; speedup 1.0000x reference)
//
#include <hip/hip_runtime.h>

typedef unsigned int u32;
typedef unsigned short u16;
typedef unsigned long long u64;
typedef float f32x4 __attribute__((ext_vector_type(4)));
typedef _Float16 f16x8 __attribute__((ext_vector_type(8)));

#define S_LEN 1024
#define NG 8      // groups (one per XCD, heuristically)
#define NM 32     // member blocks per group
#define GBAT 16   // batches per group
#define PSTR 20   // pred col stride (floats): 16B-aligned, bank-spread

__device__ __forceinline__ u16 f2h_bits(float f) {
  _Float16 h = (_Float16)f;
  return __builtin_bit_cast(u16, h);
}
__device__ __forceinline__ float h2f_bits(u16 b) {
  return (float)__builtin_bit_cast(_Float16, b);
}
__device__ __forceinline__ u32 pk2(float a, float b) {
  return (u32)f2h_bits(a) | ((u32)f2h_bits(b) << 16);
}
// u64 = two h words (lo: k, hi: k+1), each (seq<<16 | f16) -> packed f16 pair
__device__ __forceinline__ u32 pkh(u64 v) {
  return (u32)(v & 0xFFFFu) | (((u32)(v >> 32) & 0xFFFFu) << 16);
}

// Pre-arrange W into MFMA fragment-major order, fp16 (layout verified r2-r6).
// Per member m: frag[q(gate 0..3)][kc(0..15)][lane(0..63)] = uint4 (8 f16).
// Element (lane,e): k = kc*32 + (lane>>4)*8 + e ; gcol = q*512 + m*16 + (lane&15).
__global__ __launch_bounds__(256) void prep_frags(const float* __restrict__ Wi,
                                                  const float* __restrict__ Wh,
                                                  uint4* __restrict__ wf4) {
  const int blk = blockIdx.x;               // 0..63
  const int m = blk & 31;
  const float* __restrict__ W = (blk & 32) ? Wh : Wi;
  uint4* __restrict__ dst = wf4 + ((blk & 32) ? 131072 : 0) + m * 4096;
  for (int fi = threadIdx.x; fi < 4096; fi += 256) {
    const int lane = fi & 63;
    const int kc = (fi >> 6) & 15;
    const int q = fi >> 10;
    const int gq = lane >> 4, c = lane & 15;
    const int kb = kc * 32 + gq * 8;
    const int gcol = q * 512 + m * 16 + c;
    u32 wds[4];
#pragma unroll
    for (int pp = 0; pp < 4; ++pp) {
      u16 e0 = f2h_bits(W[(size_t)(kb + 2 * pp) * 2048 + gcol]);
      u16 e1 = f2h_bits(W[(size_t)(kb + 2 * pp + 1) * 2048 + gcol]);
      wds[pp] = (u32)e0 | ((u32)e1 << 16);
    }
    uint4 v; v.x = wds[0]; v.y = wds[1]; v.z = wds[2]; v.w = wds[3];
    dst[fi] = v;    // fi == (q*16+kc)*64+lane
  }
}

// Persistent LSTM. Group g = bid&7 owns batches [g*16,g*16+16);
// member m = bid>>3 owns h-indices [m*16,m*16+16).
// hbuf[2][128][512] u32, word = (seq16<<16)|f16(h).
// KEY (r8 = r7 fixed): poll reads go through L1/L2 (workgroup-scope relaxed
// atomic loads, plain cached) preceded each retry by an agent acquire fence
// (__builtin_amdgcn_fence -> waitcnt + buffer_inv). Fills from LLC are SHARED
// by the 32 group members in their XCD's L2 -> poll traffic drops ~100x vs
// sc1 LLC-direct loads (r3-r6), which congested the LLC and phase-locked
// steps at ~4.2us. Tags remain ground truth: stale/partial fills fail the
// check and retry (self-invalidating -> no livelock). Producer h stores stay
// agent-scope sc1 (write-through to LLC).
__global__ __launch_bounds__(256) void lstm_main(
    const float* __restrict__ x,
    const uint4* __restrict__ wif4,
    u32* __restrict__ hbuf,
    const float* __restrict__ bvec,
    const float* __restrict__ Wd,
    const float* __restrict__ bd,
    float* __restrict__ out) {
  __shared__ __align__(16) uint4 sWi[4096];        // 64 KB
  __shared__ __align__(16) uint4 sWh[4096];        // 64 KB
  __shared__ __align__(16) float pred[16][PSTR * 16];  // 20 KB, col-major per tile

  const int tid = threadIdx.x;
  const int lane = tid & 63;
  const int wv = tid >> 6;
  const int g = blockIdx.x & 7;
  const int m = blockIdx.x >> 3;

  for (int i = tid; i < 4096; i += 256) {
    sWi[i] = wif4[m * 4096 + i];
    sWh[i] = wif4[131072 + m * 4096 + i];
  }

  const int bt = tid >> 4;          // batch within group (output row)
  const int hi_ = tid & 15;         // h-index within member slice (output col)
  const int gb = g * GBAT + bt;
  const int hidx = m * 16 + hi_;

  const float bi = bvec[hidx];
  const float bf_ = bvec[512 + hidx];
  const float bg = bvec[1024 + hidx];
  const float bo = bvec[1536 + hidx];
  float c_reg = 0.f;

  // per-lane A-fragment source coordinates (verified r2-r6)
  const int abt = lane & 15;        // batch row this lane supplies
  const int oct = lane >> 4;        // k-octet within kc
  const float* __restrict__ xrow = x + (size_t)(g * GBAT + abt) * (S_LEN * 512);
  const u32 hrow_off = ((u32)(g * GBAT + abt)) << 9;

  __syncthreads();   // weights ready (once; vmcnt drain here is fine)

  float4 xa[8], xb[8];
#pragma unroll
  for (int kk = 0; kk < 4; ++kk) {
    const int k0 = ((wv << 2) | kk) * 32 + oct * 8;
    xa[2 * kk]     = *reinterpret_cast<const float4*>(xrow + k0);
    xa[2 * kk + 1] = *reinterpret_cast<const float4*>(xrow + k0 + 4);
  }

  auto step = [&](int t, float4* cur, float4* nxt) {
    // ---- x(t) @ Wi from prefetched regs (overlaps peers' publish propagation)
    f32x4 acc0 = {0.f, 0.f, 0.f, 0.f}, acc1 = acc0, acc2 = acc0, acc3 = acc0;
#pragma unroll
    for (int kk = 0; kk < 4; ++kk) {
      const int kc = (wv << 2) | kk;
      uint4 av;
      av.x = pk2(cur[2 * kk].x, cur[2 * kk].y);
      av.y = pk2(cur[2 * kk].z, cur[2 * kk].w);
      av.z = pk2(cur[2 * kk + 1].x, cur[2 * kk + 1].y);
      av.w = pk2(cur[2 * kk + 1].z, cur[2 * kk + 1].w);
      f16x8 af = __builtin_bit_cast(f16x8, av);
      acc0 = __builtin_amdgcn_mfma_f32_16x16x32_f16(af, __builtin_bit_cast(f16x8, sWi[(0 * 16 + kc) * 64 + lane]), acc0, 0, 0, 0);
      acc1 = __builtin_amdgcn_mfma_f32_16x16x32_f16(af, __builtin_bit_cast(f16x8, sWi[(1 * 16 + kc) * 64 + lane]), acc1, 0, 0, 0);
      acc2 = __builtin_amdgcn_mfma_f32_16x16x32_f16(af, __builtin_bit_cast(f16x8, sWi[(2 * 16 + kc) * 64 + lane]), acc2, 0, 0, 0);
      acc3 = __builtin_amdgcn_mfma_f32_16x16x32_f16(af, __builtin_bit_cast(f16x8, sWi[(3 * 16 + kc) * 64 + lane]), acc3, 0, 0, 0);
    }

    // ---- h(t) @ Wh : fence + cached poll of tagged words, then MFMA
    if (t > 0) {
      const u64* hp = reinterpret_cast<const u64*>(hbuf + (u32)(t & 1) * 65536u + hrow_off);
      const u32 want = (u32)t;
      const u64 wpat = ((u64)want << 16) | ((u64)want << 48);
      u64 raw[4][4];
      for (;;) {
        // invalidate stale L1/L2 copies; fills below come from LLC and are
        // SHARED by all group members on this XCD
        __builtin_amdgcn_fence(__ATOMIC_ACQUIRE, "agent");
#pragma unroll
        for (int kk = 0; kk < 4; ++kk) {
          const int base = (((wv << 2) | kk) << 4) | (oct << 2);
#pragma unroll
          for (int ee = 0; ee < 4; ++ee)
            raw[kk][ee] = __hip_atomic_load(hp + base + ee, __ATOMIC_RELAXED,
                                            __HIP_MEMORY_SCOPE_WORKGROUP);
        }
        __builtin_amdgcn_sched_barrier(0);  // keep checks below all loads
        u64 chk = 0;
#pragma unroll
        for (int kk = 0; kk < 4; ++kk)
#pragma unroll
          for (int ee = 0; ee < 4; ++ee)
            chk |= (raw[kk][ee] ^ wpat) & 0xFFFF0000FFFF0000ull;
        if (__all(chk == 0)) break;
        __builtin_amdgcn_s_sleep(1);
      }
      uint4 hv[4];
#pragma unroll
      for (int kk = 0; kk < 4; ++kk) {
        uint4 t4;
        t4.x = pkh(raw[kk][0]); t4.y = pkh(raw[kk][1]);
        t4.z = pkh(raw[kk][2]); t4.w = pkh(raw[kk][3]);
        hv[kk] = t4;
      }
#pragma unroll
      for (int kk = 0; kk < 4; ++kk) {
        const int kc = (wv << 2) | kk;
        f16x8 hf = __builtin_bit_cast(f16x8, hv[kk]);
        acc0 = __builtin_amdgcn_mfma_f32_16x16x32_f16(hf, __builtin_bit_cast(f16x8, sWh[(0 * 16 + kc) * 64 + lane]), acc0, 0, 0, 0);
        acc1 = __builtin_amdgcn_mfma_f32_16x16x32_f16(hf, __builtin_bit_cast(f16x8, sWh[(1 * 16 + kc) * 64 + lane]), acc1, 0, 0, 0);
        acc2 = __builtin_amdgcn_mfma_f32_16x16x32_f16(hf, __builtin_bit_cast(f16x8, sWh[(2 * 16 + kc) * 64 + lane]), acc2, 0, 0, 0);
        acc3 = __builtin_amdgcn_mfma_f32_16x16x32_f16(hf, __builtin_bit_cast(f16x8, sWh[(3 * 16 + kc) * 64 + lane]), acc3, 0, 0, 0);
      }
    }

    // ---- issue x(t+1) prefetch AFTER the fence-poll (fence drains vmcnt, so
    // prefetch issued here flies under pred/gates/publish/next-x-MFMA instead)
    {
      int tn = t + 1; tn = (tn < S_LEN) ? tn : (S_LEN - 1);
      const float* xr = xrow + (size_t)tn * 512;
#pragma unroll
      for (int kk = 0; kk < 4; ++kk) {
        const int k0 = ((wv << 2) | kk) * 32 + oct * 8;
        nxt[2 * kk]     = *reinterpret_cast<const float4*>(xr + k0);
        nxt[2 * kk + 1] = *reinterpret_cast<const float4*>(xr + k0 + 4);
      }
    }

    // ---- K-partial tiles -> pred, col-major (rows contiguous): 4x ds_write_b128
    {
      const int cc = lane & 15;
      const int r0 = (lane >> 4) << 2;
      *reinterpret_cast<f32x4*>(&pred[wv * 4 + 0][PSTR * cc + r0]) = acc0;
      *reinterpret_cast<f32x4*>(&pred[wv * 4 + 1][PSTR * cc + r0]) = acc1;
      *reinterpret_cast<f32x4*>(&pred[wv * 4 + 2][PSTR * cc + r0]) = acc2;
      *reinterpret_cast<f32x4*>(&pred[wv * 4 + 3][PSTR * cc + r0]) = acc3;
    }
    // raw barrier: drain only LDS (lgkm), NOT vmem -> prefetch stays in flight
    asm volatile("s_waitcnt lgkmcnt(0)" ::: "memory");
    __builtin_amdgcn_s_barrier();
    __builtin_amdgcn_sched_barrier(0);

    // ---- gates; publish h(t+1) with embedded tag
    {
      float gi = bi, gf = bf_, gg = bg, go = bo;
#pragma unroll
      for (int w2 = 0; w2 < 4; ++w2) {
        gi += pred[w2 * 4 + 0][PSTR * hi_ + bt];
        gf += pred[w2 * 4 + 1][PSTR * hi_ + bt];
        gg += pred[w2 * 4 + 2][PSTR * hi_ + bt];
        go += pred[w2 * 4 + 3][PSTR * hi_ + bt];
      }
      const float si = 1.f / (1.f + __expf(-gi));
      const float sf = 1.f / (1.f + __expf(-gf));
      const float so = 1.f / (1.f + __expf(-go));
      c_reg = sf * c_reg + si * tanhf(gg);
      const float hv_ = so * tanhf(c_reg);
      const u32 word = ((u32)(t + 1) << 16) | (u32)f2h_bits(hv_);
      __hip_atomic_store(hbuf + (u32)((t + 1) & 1) * 65536u + (u32)gb * 512u + (u32)hidx,
                         word, __ATOMIC_RELAXED, __HIP_MEMORY_SCOPE_AGENT);
    }
    // raw barrier: protect pred reads (this step) vs pred writes (next step);
    // own reads are complete (consumed) before arrival, so no wait needed.
    __builtin_amdgcn_s_barrier();
    __builtin_amdgcn_sched_barrier(0);
  };

  for (int t = 0; t < S_LEN; t += 2) {
    step(t, xa, xb);
    step(t + 1, xb, xa);
  }

  // ---- Dense(1) on h(S): member 0 of each group, spin on tags == S_LEN (plane 0)
  if (m == 0) {
    const int btf = tid >> 4;
    const int part = tid & 15;
    const u64* hp = reinterpret_cast<const u64*>(hbuf + (((u32)(g * GBAT + btf)) << 9));
    const u32 want = (u32)S_LEN;
    const u64 wpat = ((u64)want << 16) | ((u64)want << 48);
    u64 rawv[16];
    for (;;) {
      __builtin_amdgcn_fence(__ATOMIC_ACQUIRE, "agent");
#pragma unroll
      for (int j2 = 0; j2 < 16; ++j2)
        rawv[j2] = __hip_atomic_load(hp + part * 16 + j2, __ATOMIC_RELAXED,
                                     __HIP_MEMORY_SCOPE_WORKGROUP);
      __builtin_amdgcn_sched_barrier(0);
      u64 chk = 0;
#pragma unroll
      for (int j2 = 0; j2 < 16; ++j2)
        chk |= (rawv[j2] ^ wpat) & 0xFFFF0000FFFF0000ull;
      if (__all(chk == 0)) break;
      __builtin_amdgcn_s_sleep(1);
    }
    float acc = 0.f;
#pragma unroll
    for (int j2 = 0; j2 < 16; ++j2) {
      const int k = part * 32 + 2 * j2;
      acc += h2f_bits((u16)(rawv[j2] & 0xFFFFu)) * Wd[k] +
             h2f_bits((u16)((rawv[j2] >> 32) & 0xFFFFu)) * Wd[k + 1];
    }
#pragma unroll
    for (int s = 1; s < 16; s <<= 1) acc += __shfl_xor(acc, s, 64);
    if (part == 0) out[g * GBAT + btf] = acc + bd[0];
  }
}

extern "C" void kernel_launch(void* const* d_in, const int* in_sizes, int n_in,
                              void* d_out, int out_size, void* d_ws, size_t ws_size,
                              hipStream_t stream) {
  const float* x = (const float*)d_in[0];
  const float* Wi = (const float*)d_in[1];
  const float* Wh = (const float*)d_in[2];
  const float* bv = (const float*)d_in[3];
  const float* Wd = (const float*)d_in[4];
  const float* bd = (const float*)d_in[5];
  float* out = (float*)d_out;

  // ws layout: [0, 4MB) W frags | [4MB, 4.5MB) h ping-pong (tagged words)
  char* ws = (char*)d_ws;
  uint4* wif4 = (uint4*)ws;
  u32* hbuf = (u32*)(ws + (4u << 20));

  hipLaunchKernelGGL(prep_frags, dim3(64), dim3(256), 0, stream, Wi, Wh, wif4);

  const float* kx = x;
  const uint4* kw = wif4;
  u32* kh = hbuf;
  const float* kbv = bv;
  const float* kwd = Wd;
  const float* kbd = bd;
  float* ko = out;
  void* args[] = {&kx, &kw, &kh, &kbv, &kwd, &kbd, &ko};
  (void)hipLaunchCooperativeKernel(reinterpret_cast<void*>(lstm_main), dim3(NG * NM),
                                   dim3(256), args, 0, stream);
}

// Round 9
// 4333.863 us; speedup vs baseline: 2.3773x; 2.3773x over previous
//
#include <hip/hip_runtime.h>

typedef unsigned int u32;
typedef unsigned short u16;
typedef unsigned long long u64;
typedef float f32x4 __attribute__((ext_vector_type(4)));
typedef _Float16 f16x8 __attribute__((ext_vector_type(8)));

#define S_LEN 1024
#define NG 8      // groups (one per XCD, heuristically)
#define NM 32     // member blocks per group
#define GBAT 16   // batches per group
#define PSTR 20   // pred col stride (floats): 16B-aligned, bank-spread

__device__ __forceinline__ u16 f2h_bits(float f) {
  _Float16 h = (_Float16)f;
  return __builtin_bit_cast(u16, h);
}
__device__ __forceinline__ float h2f_bits(u16 b) {
  return (float)__builtin_bit_cast(_Float16, b);
}
__device__ __forceinline__ u32 pk2(float a, float b) {
  return (u32)f2h_bits(a) | ((u32)f2h_bits(b) << 16);
}

// Pre-arrange W into MFMA fragment-major order, fp16 (layout verified r2-r6);
// also zero the 256 flag words (per-launch -> graph-replay safe).
__global__ __launch_bounds__(256) void prep_frags(const float* __restrict__ Wi,
                                                  const float* __restrict__ Wh,
                                                  uint4* __restrict__ wf4,
                                                  u32* __restrict__ flags) {
  const int blk = blockIdx.x;               // 0..63
  if (blk == 0) flags[threadIdx.x] = 0;     // 8 groups x 32 members
  const int m = blk & 31;
  const float* __restrict__ W = (blk & 32) ? Wh : Wi;
  uint4* __restrict__ dst = wf4 + ((blk & 32) ? 131072 : 0) + m * 4096;
  for (int fi = threadIdx.x; fi < 4096; fi += 256) {
    const int lane = fi & 63;
    const int kc = (fi >> 6) & 15;
    const int q = fi >> 10;
    const int gq = lane >> 4, c = lane & 15;
    const int kb = kc * 32 + gq * 8;
    const int gcol = q * 512 + m * 16 + c;
    u32 wds[4];
#pragma unroll
    for (int pp = 0; pp < 4; ++pp) {
      u16 e0 = f2h_bits(W[(size_t)(kb + 2 * pp) * 2048 + gcol]);
      u16 e1 = f2h_bits(W[(size_t)(kb + 2 * pp + 1) * 2048 + gcol]);
      wds[pp] = (u32)e0 | ((u32)e1 << 16);
    }
    uint4 v; v.x = wds[0]; v.y = wds[1]; v.z = wds[2]; v.w = wds[3];
    dst[fi] = v;    // fi == (q*16+kc)*64+lane
  }
}

// Persistent LSTM. Group g = bid&7 owns batches [g*16,g*16+16);
// member m = bid>>3 owns h-indices [m*16,m*16+16).
// hbuf16: u16 [2][128][512] raw f16 h (untagged). flags: u32 [8][32], value =
// latest published step t+1 by that member (monotone within a run; zeroed per
// launch by prep_frags).
// KEY (r9): sync/data split. Producer: u32-packed h stores -> vmcnt(0) drain ->
// block barrier -> ONE flag store. Consumer: poll = 1 flag word/lane/retry
// (>= t, monotone), then ONE batched data read (8x u64/lane). This cuts LLC
// requests/step ~20x vs r3-r6's poll-the-data (1M x 8B requests per retry
// round = the request-rate congestion that locked steps at 4.2us).
// Safety: flags>=t proves every member completed step t-1's reads (its poll)
// before publishing h(t) -> ping-pong plane writes are race-free; max lead
// is 1 step (member at t+1 needs all flags>=t+1 incl. the laggard's).
__global__ __launch_bounds__(256) void lstm_main(
    const float* __restrict__ x,
    const uint4* __restrict__ wif4,
    u16* __restrict__ hbuf16,
    u32* __restrict__ flags,
    const float* __restrict__ bvec,
    const float* __restrict__ Wd,
    const float* __restrict__ bd,
    float* __restrict__ out) {
  __shared__ __align__(16) uint4 sWi[4096];        // 64 KB
  __shared__ __align__(16) uint4 sWh[4096];        // 64 KB
  __shared__ __align__(16) float pred[16][PSTR * 16];  // 20 KB, col-major per tile

  const int tid = threadIdx.x;
  const int lane = tid & 63;
  const int wv = tid >> 6;
  const int g = blockIdx.x & 7;
  const int m = blockIdx.x >> 3;

  for (int i = tid; i < 4096; i += 256) {
    sWi[i] = wif4[m * 4096 + i];
    sWh[i] = wif4[131072 + m * 4096 + i];
  }

  const int bt = tid >> 4;          // batch within group (output row)
  const int hi_ = tid & 15;         // h-index within member slice (output col)
  const int gb = g * GBAT + bt;
  const int hidx = m * 16 + hi_;

  const float bi = bvec[hidx];
  const float bf_ = bvec[512 + hidx];
  const float bg = bvec[1024 + hidx];
  const float bo = bvec[1536 + hidx];
  float c_reg = 0.f;

  // per-lane A-fragment source coordinates (verified r2-r6)
  const int abt = lane & 15;        // batch row this lane supplies
  const int oct = lane >> 4;        // k-octet within kc
  const float* __restrict__ xrow = x + (size_t)(g * GBAT + abt) * (S_LEN * 512);
  const u32 drow = ((u32)(g * GBAT + abt)) * 128u;  // u64 row offset in a plane
  u32* const hb32 = reinterpret_cast<u32*>(hbuf16);
  const u64* const hb64 = reinterpret_cast<const u64*>(hbuf16);
  u32* const flg = flags + g * 32;

  __syncthreads();   // weights ready (once; vmcnt drain here is fine)

  float4 xa[8], xb[8];
#pragma unroll
  for (int kk = 0; kk < 4; ++kk) {
    const int k0 = ((wv << 2) | kk) * 32 + oct * 8;
    xa[2 * kk]     = *reinterpret_cast<const float4*>(xrow + k0);
    xa[2 * kk + 1] = *reinterpret_cast<const float4*>(xrow + k0 + 4);
  }

  auto step = [&](int t, float4* cur, float4* nxt) {
    // ---- x(t) @ Wi from prefetched regs (overlaps peers' publish propagation)
    f32x4 acc0 = {0.f, 0.f, 0.f, 0.f}, acc1 = acc0, acc2 = acc0, acc3 = acc0;
#pragma unroll
    for (int kk = 0; kk < 4; ++kk) {
      const int kc = (wv << 2) | kk;
      uint4 av;
      av.x = pk2(cur[2 * kk].x, cur[2 * kk].y);
      av.y = pk2(cur[2 * kk].z, cur[2 * kk].w);
      av.z = pk2(cur[2 * kk + 1].x, cur[2 * kk + 1].y);
      av.w = pk2(cur[2 * kk + 1].z, cur[2 * kk + 1].w);
      f16x8 af = __builtin_bit_cast(f16x8, av);
      acc0 = __builtin_amdgcn_mfma_f32_16x16x32_f16(af, __builtin_bit_cast(f16x8, sWi[(0 * 16 + kc) * 64 + lane]), acc0, 0, 0, 0);
      acc1 = __builtin_amdgcn_mfma_f32_16x16x32_f16(af, __builtin_bit_cast(f16x8, sWi[(1 * 16 + kc) * 64 + lane]), acc1, 0, 0, 0);
      acc2 = __builtin_amdgcn_mfma_f32_16x16x32_f16(af, __builtin_bit_cast(f16x8, sWi[(2 * 16 + kc) * 64 + lane]), acc2, 0, 0, 0);
      acc3 = __builtin_amdgcn_mfma_f32_16x16x32_f16(af, __builtin_bit_cast(f16x8, sWi[(3 * 16 + kc) * 64 + lane]), acc3, 0, 0, 0);
    }

    // ---- wait for h(t): poll ONE flag word per lane (cheap), then read data once
    if (t > 0) {
      const u32 want = (u32)t;
      for (;;) {
        u32 fv = __hip_atomic_load(flg + (lane & 31), __ATOMIC_RELAXED,
                                   __HIP_MEMORY_SCOPE_AGENT);
        if (__all(fv >= want)) break;
        __builtin_amdgcn_s_sleep(1);
      }
      __builtin_amdgcn_sched_barrier(0);
      asm volatile("" ::: "memory");   // no data loads hoisted above the poll

      // x(t+1) prefetch: issue now so it overlaps the data-read RTT
      {
        int tn = t + 1; tn = (tn < S_LEN) ? tn : (S_LEN - 1);
        const float* xr = xrow + (size_t)tn * 512;
#pragma unroll
        for (int kk = 0; kk < 4; ++kk) {
          const int k0 = ((wv << 2) | kk) * 32 + oct * 8;
          nxt[2 * kk]     = *reinterpret_cast<const float4*>(xr + k0);
          nxt[2 * kk + 1] = *reinterpret_cast<const float4*>(xr + k0 + 4);
        }
      }

      // h data: 8 batched u64 LLC loads (race-free: writers are on the other plane)
      const u32 dbase = ((u32)(t & 1)) * 16384u + drow;
      u64 raw[4][2];
#pragma unroll
      for (int kk = 0; kk < 4; ++kk) {
        const u32 ci = dbase + (u32)(((wv << 2) | kk) * 8 + oct * 2);
        raw[kk][0] = __hip_atomic_load(hb64 + ci, __ATOMIC_RELAXED, __HIP_MEMORY_SCOPE_AGENT);
        raw[kk][1] = __hip_atomic_load(hb64 + ci + 1, __ATOMIC_RELAXED, __HIP_MEMORY_SCOPE_AGENT);
      }
      __builtin_amdgcn_sched_barrier(0);
#pragma unroll
      for (int kk = 0; kk < 4; ++kk) {
        const int kc = (wv << 2) | kk;
        uint4 t4;
        t4.x = (u32)raw[kk][0]; t4.y = (u32)(raw[kk][0] >> 32);
        t4.z = (u32)raw[kk][1]; t4.w = (u32)(raw[kk][1] >> 32);
        f16x8 hf = __builtin_bit_cast(f16x8, t4);
        acc0 = __builtin_amdgcn_mfma_f32_16x16x32_f16(hf, __builtin_bit_cast(f16x8, sWh[(0 * 16 + kc) * 64 + lane]), acc0, 0, 0, 0);
        acc1 = __builtin_amdgcn_mfma_f32_16x16x32_f16(hf, __builtin_bit_cast(f16x8, sWh[(1 * 16 + kc) * 64 + lane]), acc1, 0, 0, 0);
        acc2 = __builtin_amdgcn_mfma_f32_16x16x32_f16(hf, __builtin_bit_cast(f16x8, sWh[(2 * 16 + kc) * 64 + lane]), acc2, 0, 0, 0);
        acc3 = __builtin_amdgcn_mfma_f32_16x16x32_f16(hf, __builtin_bit_cast(f16x8, sWh[(3 * 16 + kc) * 64 + lane]), acc3, 0, 0, 0);
      }
    } else {
      // t == 0: no h; still prefetch x(1)
      const float* xr = xrow + 512;
#pragma unroll
      for (int kk = 0; kk < 4; ++kk) {
        const int k0 = ((wv << 2) | kk) * 32 + oct * 8;
        nxt[2 * kk]     = *reinterpret_cast<const float4*>(xr + k0);
        nxt[2 * kk + 1] = *reinterpret_cast<const float4*>(xr + k0 + 4);
      }
    }

    // ---- K-partial tiles -> pred, col-major (rows contiguous): 4x ds_write_b128
    {
      const int cc = lane & 15;
      const int r0 = (lane >> 4) << 2;
      *reinterpret_cast<f32x4*>(&pred[wv * 4 + 0][PSTR * cc + r0]) = acc0;
      *reinterpret_cast<f32x4*>(&pred[wv * 4 + 1][PSTR * cc + r0]) = acc1;
      *reinterpret_cast<f32x4*>(&pred[wv * 4 + 2][PSTR * cc + r0]) = acc2;
      *reinterpret_cast<f32x4*>(&pred[wv * 4 + 3][PSTR * cc + r0]) = acc3;
    }
    // raw barrier: drain only LDS (lgkm), NOT vmem -> prefetch stays in flight
    asm volatile("s_waitcnt lgkmcnt(0)" ::: "memory");
    __builtin_amdgcn_s_barrier();
    __builtin_amdgcn_sched_barrier(0);

    // ---- gates; publish h(t+1): packed u32 stores -> drain -> barrier -> flag
    {
      float gi = bi, gf = bf_, gg = bg, go = bo;
#pragma unroll
      for (int w2 = 0; w2 < 4; ++w2) {
        gi += pred[w2 * 4 + 0][PSTR * hi_ + bt];
        gf += pred[w2 * 4 + 1][PSTR * hi_ + bt];
        gg += pred[w2 * 4 + 2][PSTR * hi_ + bt];
        go += pred[w2 * 4 + 3][PSTR * hi_ + bt];
      }
      const float si = 1.f / (1.f + __expf(-gi));
      const float sf = 1.f / (1.f + __expf(-gf));
      const float so = 1.f / (1.f + __expf(-go));
      c_reg = sf * c_reg + si * tanhf(gg);
      const float hv_ = so * tanhf(c_reg);
      const u32 hb = (u32)f2h_bits(hv_);
      const u32 partner = __shfl_xor(hb, 1, 64);   // hi_ bit0 == lane bit0
      if ((hi_ & 1) == 0) {
        const u32 word = hb | (partner << 16);     // [hidx]=lo, [hidx+1]=hi
        const u32 wi_ = ((u32)((t + 1) & 1)) * 32768u + (u32)gb * 256u + ((u32)hidx >> 1);
        __hip_atomic_store(hb32 + wi_, word, __ATOMIC_RELAXED, __HIP_MEMORY_SCOPE_AGENT);
      }
    }
    // drain own h stores (also x prefetch - already ~done), then block-wide barrier
    asm volatile("s_waitcnt vmcnt(0)" ::: "memory");
    __builtin_amdgcn_s_barrier();   // all waves' stores at LLC; also protects pred
    __builtin_amdgcn_sched_barrier(0);
    if (tid == 0)
      __hip_atomic_store(flg + m, (u32)(t + 1), __ATOMIC_RELAXED, __HIP_MEMORY_SCOPE_AGENT);
  };

  for (int t = 0; t < S_LEN; t += 2) {
    step(t, xa, xb);
    step(t + 1, xb, xa);
  }

  // ---- Dense(1) on h(S): member 0 of each group; h(1024) is in plane 0
  if (m == 0) {
    const int btf = tid >> 4;
    const int part = tid & 15;
    for (;;) {
      u32 fv = __hip_atomic_load(flg + (lane & 31), __ATOMIC_RELAXED,
                                 __HIP_MEMORY_SCOPE_AGENT);
      if (__all(fv >= (u32)S_LEN)) break;
      __builtin_amdgcn_s_sleep(1);
    }
    __builtin_amdgcn_sched_barrier(0);
    asm volatile("" ::: "memory");
    const u32 rbase = ((u32)(g * GBAT + btf)) * 128u + (u32)part * 8u;
    u64 rawv[8];
#pragma unroll
    for (int j = 0; j < 8; ++j)
      rawv[j] = __hip_atomic_load(hb64 + rbase + j, __ATOMIC_RELAXED,
                                  __HIP_MEMORY_SCOPE_AGENT);
    __builtin_amdgcn_sched_barrier(0);
    float acc = 0.f;
#pragma unroll
    for (int j = 0; j < 8; ++j) {
      const int k = part * 32 + 4 * j;
      acc += h2f_bits((u16)(rawv[j] & 0xFFFFu)) * Wd[k] +
             h2f_bits((u16)((rawv[j] >> 16) & 0xFFFFu)) * Wd[k + 1] +
             h2f_bits((u16)((rawv[j] >> 32) & 0xFFFFu)) * Wd[k + 2] +
             h2f_bits((u16)((rawv[j] >> 48) & 0xFFFFu)) * Wd[k + 3];
    }
#pragma unroll
    for (int s = 1; s < 16; s <<= 1) acc += __shfl_xor(acc, s, 64);
    if (part == 0) out[g * GBAT + btf] = acc + bd[0];
  }
}

extern "C" void kernel_launch(void* const* d_in, const int* in_sizes, int n_in,
                              void* d_out, int out_size, void* d_ws, size_t ws_size,
                              hipStream_t stream) {
  const float* x = (const float*)d_in[0];
  const float* Wi = (const float*)d_in[1];
  const float* Wh = (const float*)d_in[2];
  const float* bv = (const float*)d_in[3];
  const float* Wd = (const float*)d_in[4];
  const float* bd = (const float*)d_in[5];
  float* out = (float*)d_out;

  // ws: [0,4MB) W frags | [4MB,4.25MB) h u16 ping-pong | [+1KB) flags
  char* ws = (char*)d_ws;
  uint4* wif4 = (uint4*)ws;
  u16* hbuf16 = (u16*)(ws + (4u << 20));
  u32* flags = (u32*)(ws + (4u << 20) + (256u << 10));

  hipLaunchKernelGGL(prep_frags, dim3(64), dim3(256), 0, stream, Wi, Wh, wif4, flags);

  const float* kx = x;
  const uint4* kw = wif4;
  u16* kh = hbuf16;
  u32* kf = flags;
  const float* kbv = bv;
  const float* kwd = Wd;
  const float* kbd = bd;
  float* ko = out;
  void* args[] = {&kx, &kw, &kh, &kf, &kbv, &kwd, &kbd, &ko};
  (void)hipLaunchCooperativeKernel(reinterpret_cast<void*>(lstm_main), dim3(NG * NM),
                                   dim3(256), args, 0, stream);
}